// Round 3
// baseline (216.698 us; speedup 1.0000x reference)
//
#include <hip/hip_runtime.h>
#include <hip/hip_bf16.h>

// Self-attention: B=4, S=2048, D=768, fp32 in/out, bf16 MFMA internally.
// R9: PV moved to the 8-phase 256x256 kernel via K-split x2:
//   grid (8 q, 3 e, 4 batch x 2 half) = 192 blocks, 1/CU, K=1024 (16 K-tiles)
//   each — the verified 8-phase per-CU rate (~6.1 GF/us/CU) beats the 2-phase
//   PV's ~920 TF ceiling. Half-0 numerators -> out, half-1 -> p1 (aliases the
//   dead Xb|W^T|Qb region — zero extra ws); per-half rowsums via ones-MFMA ->
//   rs[2][4][2048]. pv_combine streams out=(out+p1)/(rs0+rs1) (~75 MB).
// QKV stays 128x128 2-phase (its R8 56us vs R6 44.5us was session clock —
// same code, same bytes, hbm_gbps scaled exactly with dur).
// Es stays 256x256 8-phase (256-block perfect fit, ~1.4 PF).
// ws: Xb | WqT WkT WvT | Qb Kb Vt | Es   (p1/rs alias [0 .. 25.3 MB))

typedef __attribute__((ext_vector_type(8))) short short8;
typedef __attribute__((ext_vector_type(4))) short short4v;
typedef __attribute__((ext_vector_type(4))) float float4v;

static constexpr int B_ = 4, S_ = 2048, D_ = 768;
static constexpr int MS = B_ * S_;  // 8192

__device__ inline short f2bf(float f) {
  __hip_bfloat16 h = __float2bfloat16(f);
  union { __hip_bfloat16 h; short s; } u; u.h = h; return u.s;
}

typedef const __attribute__((address_space(1))) unsigned int g_u32;
typedef __attribute__((address_space(3))) unsigned int l_u32;

__device__ __forceinline__ void glds16(const short* g, short* l) {
  __builtin_amdgcn_global_load_lds((g_u32*)g, (l_u32*)l, 16, 0, 0);
}

__global__ __launch_bounds__(256)
void cast_f32_bf16(const float* __restrict__ x, short* __restrict__ y, int n) {
  int i = (blockIdx.x * 256 + threadIdx.x) * 4;
  if (i + 3 < n) {
    float4v v = *(const float4v*)(x + i);
    short4v o;
    o.x = f2bf(v.x); o.y = f2bf(v.y); o.z = f2bf(v.z); o.w = f2bf(v.w);
    *(short4v*)(y + i) = o;
  }
}

// T[e][d] = (bf16) W[d][e], for three 768x768 matrices
__global__ void transpose_cast_w(const float* __restrict__ W0, const float* __restrict__ W1,
                                 const float* __restrict__ W2,
                                 short* __restrict__ T0, short* __restrict__ T1,
                                 short* __restrict__ T2) {
  const float* W = blockIdx.z == 0 ? W0 : (blockIdx.z == 1 ? W1 : W2);
  short* T = blockIdx.z == 0 ? T0 : (blockIdx.z == 1 ? T1 : T2);
  __shared__ float tile[32][33];
  int bx = blockIdx.x * 32, by = blockIdx.y * 32;
  int tx = threadIdx.x, ty = threadIdx.y;
  for (int r = ty; r < 32; r += 8)
    tile[r][tx] = W[(by + r) * D_ + bx + tx];
  __syncthreads();
  for (int r = ty; r < 32; r += 8)
    T[(bx + r) * D_ + by + tx] = f2bf(tile[tx][r]);
}

// out[qg][e] = (out[qg][e] + p1[qg][e]) / (rs[qg] + rs[8192+qg]),  qg=b*2048+q
__global__ __launch_bounds__(256)
void pv_combine(const float* __restrict__ p1, const float* __restrict__ rs,
                float* __restrict__ out) {
  long i = ((long)blockIdx.x * 256 + threadIdx.x) * 4;  // 8192*768 total
  long qg = i / 768;                                    // row (768 % 4 == 0)
  float inv = 1.0f / (rs[qg] + rs[8192 + qg]);
  float4v a = *(const float4v*)(out + i);
  float4v p = *(const float4v*)(p1 + i);
  float4v o;
#pragma unroll
  for (int r = 0; r < 4; r++) o[r] = (a[r] + p[r]) * inv;
  *(float4v*)(out + i) = o;
}

// ---------------------------------------------------------------------------
// 128x128 2-phase kernel — QKV (EPI 0) only.
// ---------------------------------------------------------------------------
template<int EPI, int TM, int TN>
__global__ __launch_bounds__(256)
void gemm_bt(const short* __restrict__ A, const short* __restrict__ Bt,
             void* __restrict__ C0v, short* __restrict__ C1, short* __restrict__ C2,
             const float* __restrict__ bias0, const float* __restrict__ bias1,
             const float* __restrict__ bias2,
             int K, int lda, int ldb, int ldc,
             long sA, long sB, long sC, float scale) {
  constexpr int BMv = TM * 32, BNv = TN * 32;
  const int b = blockIdx.z;
  A += (long)b * sA;
  Bt += (long)b * sB;
  short* Cs = (short*)C0v + (long)b * sC;

  __shared__ short As[BMv * 64];
  __shared__ short Bs[BNv * 64];

  const int t = threadIdx.x;
  const int wave = t >> 6, lane = t & 63;
  const int lane16 = lane & 15, q = lane >> 4;
  const int m0 = blockIdx.y * BMv, n0 = blockIdx.x * BNv;
  const int wm = (wave >> 1) * (TM * 16), wn = (wave & 1) * (TN * 16);
  const int rsub = lane >> 3;
  const int g = (lane & 7) ^ rsub;

  auto stage = [&](int kk) {
#pragma unroll
    for (int i = wave; i < BMv / 8; i += 4)
      glds16(A + (long)(m0 + i * 8 + rsub) * lda + kk + g * 8, &As[i * 512]);
#pragma unroll
    for (int i = wave; i < BNv / 8; i += 4)
      glds16(Bt + (long)(n0 + i * 8 + rsub) * ldb + kk + g * 8, &Bs[i * 512]);
  };

  stage(0);

  float4v acc[TM][TN];
#pragma unroll
  for (int i = 0; i < TM; i++)
#pragma unroll
    for (int j = 0; j < TN; j++) acc[i][j] = {0.f, 0.f, 0.f, 0.f};

  for (int k0 = 0; k0 < K; k0 += 64) {
    __syncthreads();  // B1: drains stage(k0) [vmcnt(0)] + wave sync

    short8 af[2][TM], bfr[2][TN];
#pragma unroll
    for (int s = 0; s < 2; s++) {
#pragma unroll
      for (int i = 0; i < TM; i++) {
        int R = wm + i * 16 + lane16;
        af[s][i] = *(const short8*)&As[R * 64 + (((s * 4 + q) ^ (R & 7)) * 8)];
      }
#pragma unroll
      for (int j = 0; j < TN; j++) {
        int R = wn + j * 16 + lane16;
        bfr[s][j] = *(const short8*)&Bs[R * 64 + (((s * 4 + q) ^ (R & 7)) * 8)];
      }
    }
    __syncthreads();  // B2: all waves done reading LDS

    if (k0 + 64 < K) stage(k0 + 64);  // async; overlaps the MFMA pack below

#pragma unroll
    for (int s = 0; s < 2; s++) {
#pragma unroll
      for (int i = 0; i < TM; i++) {
#pragma unroll
        for (int j = 0; j < TN; j++)
          acc[i][j] = __builtin_amdgcn_mfma_f32_16x16x32_bf16(af[s][i], bfr[s][j], acc[i][j], 0, 0, 0);
      }
    }
  }

  // EPI 0: QKV tri-output
#pragma unroll
  for (int i = 0; i < TM; i++) {
    int mrow = m0 + wm + i * 16 + q * 4;
#pragma unroll
    for (int j = 0; j < TN; j++) {
      int ncol = n0 + wn + j * 16 + lane16;   // tile-uniform branch: bounds %16
      if (ncol < 1536) {
        short* dst = ncol < 768 ? Cs : C1;
        const float* bs = ncol < 768 ? bias0 : bias1;
        int c = ncol < 768 ? ncol : ncol - 768;   // NOT `& 767` (768 != pow2)
#pragma unroll
        for (int rr = 0; rr < 4; rr++)
          dst[(long)(mrow + rr) * 768 + c] = f2bf(acc[i][j][rr] + bs[c]);
      } else {
        int e = ncol - 1536;
        float bv = bias2[e];
        short4v o;
#pragma unroll
        for (int rr = 0; rr < 4; rr++) o[rr] = f2bf(acc[i][j][rr] + bv);
        *(short4v*)&C2[(long)e * MS + mrow] = o;   // Vt[e][m], 8-B store
      }
    }
  }
}

// ---------------------------------------------------------------------------
// 256x256 8-phase kernel. EPI 2: Es = exp(scale*QK^T) (grid 8x8x4 = 256 blk).
// EPI 5: PV K-split half — blockIdx.z = b*2 + half; numerator partial to
// out (half 0) / p1 (half 1) as fp32 [q][e] with float4 stores; per-half
// rowsum(Es row q) via ones-MFMA -> rs[half][b][q].
// 512 thr = 8 waves (2Mx4N), wave tile 128x64, BK=64, LDS 128 KiB dbuf.
// ---------------------------------------------------------------------------
template<int EPI>
__global__ __launch_bounds__(512, 2)
void gemm8p(const short* __restrict__ A, const short* __restrict__ Bt,
            void* __restrict__ C0v, short* __restrict__ C1, short* __restrict__ C2,
            const float* __restrict__ bias0, const float* __restrict__ bias1,
            const float* __restrict__ bias2,
            int K, int lda, int ldb, int ldc,
            long sA, long sB, long sC, float scale) {
  int b = blockIdx.z, hh = 0;
  if (EPI == 5) { hh = b & 1; b >>= 1; }
  A += (long)b * sA + (EPI == 5 ? hh * 1024 : 0);
  Bt += (long)b * sB + (EPI == 5 ? hh * 1024 : 0);
  short* Cs = (short*)C0v + (long)b * sC;

  __shared__ short As[2][256 * 64];   // [buf][row][64 shorts = 128 B, swizzled]
  __shared__ short Bs[2][256 * 64];

  const int t = threadIdx.x;
  const int wave = t >> 6, lane = t & 63;
  const int lane16 = lane & 15, q = lane >> 4;
  const int xr = lane16 & 7;            // row&7 for all fragment reads
  const int m0 = blockIdx.y * 256, n0 = blockIdx.x * 256;
  const int wm = (wave >> 2) * 128, wn = (wave & 3) * 64;
  const int rsub = lane >> 3;           // row within an 8-row / 1 KB wave-instr
  const int g = (lane & 7) ^ rsub;      // swizzled source chunk
  const int nt = K >> 6;

  // A stage-unit u: rows {u*64..u*64+63} U {128+u*64..}, dead after phase 1/3
  auto stageA = [&](int u, int tt) {
    short* dst = &As[tt & 1][0];
    const short* src = A + tt * 64 + g * 8;
#pragma unroll
    for (int r = 0; r < 2; r++) {
      int row0 = u * 64 + r * 128 + wave * 8;
      glds16(src + (long)(m0 + row0 + rsub) * lda, dst + row0 * 64);
    }
  };
  // B stage-unit u: rows {64k+u*32 .. 64k+u*32+31}, dead after phase 1/2
  auto stageB = [&](int u, int tt) {
    short* dst = &Bs[tt & 1][0];
    const short* src = Bt + tt * 64 + g * 8;
#pragma unroll
    for (int r = 0; r < 2; r++) {
      int idx = r * 8 + wave;
      int row0 = (idx >> 2) * 64 + u * 32 + (idx & 3) * 8;
      glds16(src + (long)(n0 + row0 + rsub) * ldb, dst + row0 * 64);
    }
  };

  float4v acc[8][4];
#pragma unroll
  for (int i = 0; i < 8; i++)
#pragma unroll
    for (int j = 0; j < 4; j++) acc[i][j] = {0.f, 0.f, 0.f, 0.f};

  // EPI 5 rowsum accumulators (dead-code otherwise); index = global n-frag j
  float4v acc_rs[4];
#pragma unroll
  for (int j = 0; j < 4; j++) acc_rs[j] = {0.f, 0.f, 0.f, 0.f};
  short8 ones;
#pragma unroll
  for (int e = 0; e < 8; e++) ones[e] = (short)0x3F80;  // bf16 1.0

  // prologue: tile0 fully, tile1 first 3 units (order = steady-state order)
  stageA(0, 0); stageA(1, 0); stageB(0, 0); stageB(1, 0);
  if (nt > 1) { stageA(0, 1); stageB(0, 1); stageA(1, 1); }
  if (nt > 1) asm volatile("s_waitcnt vmcnt(6)" ::: "memory");
  else        asm volatile("s_waitcnt vmcnt(0)" ::: "memory");
  __builtin_amdgcn_s_barrier();

#pragma unroll 2
  for (int tt = 0; tt < nt; ++tt) {
    const short* Ab = &As[tt & 1][0];
    const short* Bb = &Bs[tt & 1][0];
    short8 a[4][2], b0[2][2], b1[2][2];

    // ---- phase 1: quadrant (mh0, nh0); stage (tt+1).B-u1 into other buf
#pragma unroll
    for (int ii = 0; ii < 4; ii++) {
      int R = wm + ii * 16 + lane16;
#pragma unroll
      for (int s = 0; s < 2; s++)
        a[ii][s] = *(const short8*)&Ab[R * 64 + (((s * 4 + q) ^ xr) * 8)];
    }
#pragma unroll
    for (int jj = 0; jj < 2; jj++) {
      int R = wn + jj * 16 + lane16;
#pragma unroll
      for (int s = 0; s < 2; s++)
        b0[jj][s] = *(const short8*)&Bb[R * 64 + (((s * 4 + q) ^ xr) * 8)];
    }
    if (tt + 1 < nt) stageB(1, tt + 1);
    __builtin_amdgcn_s_barrier();
    asm volatile("s_waitcnt lgkmcnt(0)" ::: "memory");
    __builtin_amdgcn_sched_barrier(0);
    __builtin_amdgcn_s_setprio(1);
#pragma unroll
    for (int s = 0; s < 2; s++)
#pragma unroll
      for (int ii = 0; ii < 4; ii++)
#pragma unroll
        for (int jj = 0; jj < 2; jj++)
          acc[ii][jj] = __builtin_amdgcn_mfma_f32_16x16x32_bf16(a[ii][s], b0[jj][s], acc[ii][jj], 0, 0, 0);
    if (EPI == 5) {
#pragma unroll
      for (int s = 0; s < 2; s++)
#pragma unroll
        for (int jj = 0; jj < 2; jj++)
          acc_rs[jj] = __builtin_amdgcn_mfma_f32_16x16x32_bf16(ones, b0[jj][s], acc_rs[jj], 0, 0, 0);
    }
    __builtin_amdgcn_s_setprio(0);
    __builtin_amdgcn_s_barrier();

    // ---- phase 2: quadrant (mh0, nh1); stage (tt+2).A-u0 (dead since ph1)
#pragma unroll
    for (int jj = 0; jj < 2; jj++) {
      int R = wn + 32 + jj * 16 + lane16;
#pragma unroll
      for (int s = 0; s < 2; s++)
        b1[jj][s] = *(const short8*)&Bb[R * 64 + (((s * 4 + q) ^ xr) * 8)];
    }
    if (tt + 2 < nt) stageA(0, tt + 2);
    __builtin_amdgcn_s_barrier();
    asm volatile("s_waitcnt lgkmcnt(0)" ::: "memory");
    __builtin_amdgcn_sched_barrier(0);
    __builtin_amdgcn_s_setprio(1);
#pragma unroll
    for (int s = 0; s < 2; s++)
#pragma unroll
      for (int ii = 0; ii < 4; ii++)
#pragma unroll
        for (int jj = 0; jj < 2; jj++)
          acc[ii][2 + jj] = __builtin_amdgcn_mfma_f32_16x16x32_bf16(a[ii][s], b1[jj][s], acc[ii][2 + jj], 0, 0, 0);
    if (EPI == 5) {
#pragma unroll
      for (int s = 0; s < 2; s++)
#pragma unroll
        for (int jj = 0; jj < 2; jj++)
          acc_rs[2 + jj] = __builtin_amdgcn_mfma_f32_16x16x32_bf16(ones, b1[jj][s], acc_rs[2 + jj], 0, 0, 0);
    }
    __builtin_amdgcn_s_setprio(0);
    __builtin_amdgcn_s_barrier();

    // ---- phase 3: quadrant (mh1, nh1); A-u1 reads; stage (tt+2).B-u0
#pragma unroll
    for (int ii = 0; ii < 4; ii++) {
      int R = wm + 64 + ii * 16 + lane16;
#pragma unroll
      for (int s = 0; s < 2; s++)
        a[ii][s] = *(const short8*)&Ab[R * 64 + (((s * 4 + q) ^ xr) * 8)];
    }
    if (tt + 2 < nt) stageB(0, tt + 2);
    __builtin_amdgcn_s_barrier();
    asm volatile("s_waitcnt lgkmcnt(0)" ::: "memory");
    __builtin_amdgcn_sched_barrier(0);
    __builtin_amdgcn_s_setprio(1);
#pragma unroll
    for (int s = 0; s < 2; s++)
#pragma unroll
      for (int ii = 0; ii < 4; ii++)
#pragma unroll
        for (int jj = 0; jj < 2; jj++)
          acc[4 + ii][2 + jj] = __builtin_amdgcn_mfma_f32_16x16x32_bf16(a[ii][s], b1[jj][s], acc[4 + ii][2 + jj], 0, 0, 0);
    __builtin_amdgcn_s_setprio(0);
    __builtin_amdgcn_s_barrier();

    // ---- phase 4: quadrant (mh1, nh0); stage (tt+2).A-u1 (dead since ph3);
    //      counted vmcnt — guarantees tile tt+1 staged, 3 half-tiles in flight
    if (tt + 2 < nt) stageA(1, tt + 2);
    __builtin_amdgcn_s_barrier();
    __builtin_amdgcn_s_setprio(1);
#pragma unroll
    for (int s = 0; s < 2; s++)
#pragma unroll
      for (int ii = 0; ii < 4; ii++)
#pragma unroll
        for (int jj = 0; jj < 2; jj++)
          acc[4 + ii][jj] = __builtin_amdgcn_mfma_f32_16x16x32_bf16(a[ii][s], b0[jj][s], acc[4 + ii][jj], 0, 0, 0);
    __builtin_amdgcn_s_setprio(0);
    if (tt + 2 < nt) asm volatile("s_waitcnt vmcnt(6)" ::: "memory");
    else             asm volatile("s_waitcnt vmcnt(0)" ::: "memory");
    __builtin_amdgcn_s_barrier();
  }

  if (EPI == 2) {
    // bf16 out = exp(acc*scale)
#pragma unroll
    for (int i = 0; i < 8; i++) {
      int mrow = m0 + wm + i * 16 + q * 4;
#pragma unroll
      for (int j = 0; j < 4; j++) {
        int ncol = n0 + wn + j * 16 + lane16;
#pragma unroll
        for (int rr = 0; rr < 4; rr++)
          Cs[(long)(mrow + rr) * ldc + ncol] = f2bf(__expf(acc[i][j][rr] * scale));
      }
    }
  } else {
    // EPI 5: rows = e, cols = q. Numerator partial, float4 stores; rowsums.
    float* dst = (hh ? (float*)C1 : (float*)C0v) + (long)b * S_ * 768;
    float* rsb = (float*)C2 + (long)hh * 8192 + (long)b * 2048;
    if (wm == 0 && q == 0) {   // waves 0-3, lanes 0-15: one writer per q-col
#pragma unroll
      for (int j = 0; j < 4; j++) {
        int ncol = n0 + wn + j * 16 + lane16;
        rsb[ncol] = acc_rs[j][0];   // rr/m-independent by C/D layout
      }
    }
#pragma unroll
    for (int i = 0; i < 8; i++) {
      int mrow = m0 + wm + i * 16 + q * 4;   // e, %4 == 0
#pragma unroll
      for (int j = 0; j < 4; j++) {
        int ncol = n0 + wn + j * 16 + lane16;  // q token
        *(float4v*)&dst[(long)ncol * ldc + mrow] = acc[i][j];  // 16-B aligned
      }
    }
  }
}

extern "C" void kernel_launch(void* const* d_in, const int* in_sizes, int n_in,
                              void* d_out, int out_size, void* d_ws, size_t ws_size,
                              hipStream_t stream) {
  const float* x  = (const float*)d_in[0];
  const float* Wq = (const float*)d_in[1];
  const float* bq = (const float*)d_in[2];
  const float* Wk = (const float*)d_in[3];
  const float* bk = (const float*)d_in[4];
  const float* Wv = (const float*)d_in[5];
  const float* bv = (const float*)d_in[6];
  float* out = (float*)d_out;

  short* Xb  = (short*)d_ws;                     // [8192][768]
  short* WqT = Xb + (long)MS * D_;               // [2304][768] = WqT||WkT||WvT
  short* WkT = WqT + (long)D_ * D_;
  short* WvT = WkT + (long)D_ * D_;
  short* Qb  = WvT + (long)D_ * D_;              // [8192][768]
  short* Kb  = Qb + (long)MS * D_;               // [8192][768]
  short* Vt  = Kb + (long)MS * D_;               // [768][8192]
  short* Es  = Vt + (long)MS * D_;               // [4][2048][2048] exp(scores)

  // PV scratch aliases the region dead after Es: Xb | W^T | first 2/3 of Qb.
  float* p1f = (float*)d_ws;                     // [8192][768] fp32 numerators
  float* rsf = p1f + (long)MS * D_;              // [2][4][2048] rowsum halves

  cast_f32_bf16<<<(MS * D_) / 1024, 256, 0, stream>>>(x, Xb, MS * D_);
  transpose_cast_w<<<dim3(24, 24, 3), dim3(32, 8), 0, stream>>>(Wq, Wk, Wv, WqT, WkT, WvT);

  // Q||K||Vt = Xb @ [WqT;WkT;WvT]^T + biases  (128x128 2-phase, 18x64 blk)
  gemm_bt<0, 4, 4><<<dim3(2304 / 128, MS / 128, 1), 256, 0, stream>>>(
      Xb, WqT, Qb, Kb, Vt, bq, bk, bv,
      D_, D_, D_, D_, 0, 0, 0, 1.0f);
  // Es[b,q,k] = exp((Qb[b] @ Kb[b]^T)/sqrt(D)) -> bf16  (8x8x4 = 256 blk, 8-phase)
  gemm8p<2><<<dim3(S_ / 256, S_ / 256, B_), 512, 0, stream>>>(
      Qb, Kb, Es, nullptr, nullptr, nullptr, nullptr, nullptr,
      D_, D_, D_, S_,
      (long)S_ * D_, (long)S_ * D_, (long)S_ * S_, 1.0f / sqrtf((float)D_));
  // PV K-split halves: C'[e][q] partial = Vt[b][:, kwin] @ Es[b][:, kwin]^T
  // grid (8 q, 3 e, 8 = b*2+half) = 192 blocks, K=1024 each (8-phase)
  gemm8p<5><<<dim3(S_ / 256, D_ / 256, B_ * 2), 512, 0, stream>>>(
      Vt, Es, out, (short*)p1f, (short*)rsf, nullptr, nullptr, nullptr,
      1024, MS, S_, D_,
      (long)S_, (long)S_ * S_, 0, 1.0f);
  // out = (out + p1) / (rs0 + rs1)
  pv_combine<<<(MS * D_) / 1024, 256, 0, stream>>>(p1f, rsf, out);
}

// Round 4
// 203.985 us; speedup vs baseline: 1.0623x; 1.0623x over previous
//
#include <hip/hip_runtime.h>
#include <hip/hip_bf16.h>

// Self-attention: B=4, S=2048, D=768, fp32 in/out, bf16 MFMA internally.
// R10: PV reverted to the flipped 2-phase full-K kernel (R8's EPI 4 — no
// K-split, no fp32 partials, no combine pass), and the two PV operand
// streams get channel-rotating row pads:
//   Vt ld 8192 -> 8256 shorts (16512 B = 64.5 x 256 B)
//   Es ld 2048 -> 2112 shorts ( 4224 B = 16.5 x 256 B)
// Theory: both PV streams had row strides = 0 mod 4 KB, so every 8-row
// glds16 staging instruction hit one L2 channel set (serialized returns) —
// explaining PV running at ~2x below structure ceiling in BOTH the 2-phase
// (R8, ~50us vs ~28 expected) and 8-phase (R9, 29% per-CU MfmaUtil vs Es's
// 56%) schedules. Padding makes consecutive rows rotate channels.
// QKV stays 128x128 2-phase; Es stays 256x256 8-phase (256-blk perfect fit).
// ws: Xb | WqT WkT WvT | Qb Kb | Vt(pad) | Es(pad)

typedef __attribute__((ext_vector_type(8))) short short8;
typedef __attribute__((ext_vector_type(4))) short short4v;
typedef __attribute__((ext_vector_type(4))) float float4v;

static constexpr int B_ = 4, S_ = 2048, D_ = 768;
static constexpr int MS = B_ * S_;   // 8192
static constexpr int VLD = 8256;     // Vt leading dim (pad: 16512 B = 64.5 ch)
static constexpr int ELD = 2112;     // Es leading dim (pad:  4224 B = 16.5 ch)

__device__ inline short f2bf(float f) {
  __hip_bfloat16 h = __float2bfloat16(f);
  union { __hip_bfloat16 h; short s; } u; u.h = h; return u.s;
}

typedef const __attribute__((address_space(1))) unsigned int g_u32;
typedef __attribute__((address_space(3))) unsigned int l_u32;

__device__ __forceinline__ void glds16(const short* g, short* l) {
  __builtin_amdgcn_global_load_lds((g_u32*)g, (l_u32*)l, 16, 0, 0);
}

__global__ __launch_bounds__(256)
void cast_f32_bf16(const float* __restrict__ x, short* __restrict__ y, int n) {
  int i = (blockIdx.x * 256 + threadIdx.x) * 4;
  if (i + 3 < n) {
    float4v v = *(const float4v*)(x + i);
    short4v o;
    o.x = f2bf(v.x); o.y = f2bf(v.y); o.z = f2bf(v.z); o.w = f2bf(v.w);
    *(short4v*)(y + i) = o;
  }
}

// T[e][d] = (bf16) W[d][e], for three 768x768 matrices
__global__ void transpose_cast_w(const float* __restrict__ W0, const float* __restrict__ W1,
                                 const float* __restrict__ W2,
                                 short* __restrict__ T0, short* __restrict__ T1,
                                 short* __restrict__ T2) {
  const float* W = blockIdx.z == 0 ? W0 : (blockIdx.z == 1 ? W1 : W2);
  short* T = blockIdx.z == 0 ? T0 : (blockIdx.z == 1 ? T1 : T2);
  __shared__ float tile[32][33];
  int bx = blockIdx.x * 32, by = blockIdx.y * 32;
  int tx = threadIdx.x, ty = threadIdx.y;
  for (int r = ty; r < 32; r += 8)
    tile[r][tx] = W[(by + r) * D_ + bx + tx];
  __syncthreads();
  for (int r = ty; r < 32; r += 8)
    T[(bx + r) * D_ + by + tx] = f2bf(tile[tx][r]);
}

// ---------------------------------------------------------------------------
// 128x128 2-phase kernel. EPI 0: QKV tri-output. EPI 4: flipped PV —
// C'[e][q] = sum_k Vt[e][k]*Es[q][k]; out[q][e] = C'/rowsum_q, float4 stores.
// ---------------------------------------------------------------------------
template<int EPI, int TM, int TN>
__global__ __launch_bounds__(256)
void gemm_bt(const short* __restrict__ A, const short* __restrict__ Bt,
             void* __restrict__ C0v, short* __restrict__ C1, short* __restrict__ C2,
             const float* __restrict__ bias0, const float* __restrict__ bias1,
             const float* __restrict__ bias2,
             int K, int lda, int ldb, int ldc,
             long sA, long sB, long sC, float scale) {
  constexpr int BMv = TM * 32, BNv = TN * 32;
  const int b = blockIdx.z;
  A += (long)b * sA;
  Bt += (long)b * sB;
  float* Cf = (float*)C0v + (long)b * sC;
  short* Cs = (short*)C0v + (long)b * sC;

  __shared__ short As[BMv * 64];
  __shared__ short Bs[BNv * 64];

  const int t = threadIdx.x;
  const int wave = t >> 6, lane = t & 63;
  const int lane16 = lane & 15, q = lane >> 4;
  const int m0 = blockIdx.y * BMv, n0 = blockIdx.x * BNv;
  const int wm = (wave >> 1) * (TM * 16), wn = (wave & 1) * (TN * 16);
  const int rsub = lane >> 3;
  const int g = (lane & 7) ^ rsub;

  auto stage = [&](int kk) {
#pragma unroll
    for (int i = wave; i < BMv / 8; i += 4)
      glds16(A + (long)(m0 + i * 8 + rsub) * lda + kk + g * 8, &As[i * 512]);
#pragma unroll
    for (int i = wave; i < BNv / 8; i += 4)
      glds16(Bt + (long)(n0 + i * 8 + rsub) * ldb + kk + g * 8, &Bs[i * 512]);
  };

  stage(0);

  float4v acc[TM][TN];
#pragma unroll
  for (int i = 0; i < TM; i++)
#pragma unroll
    for (int j = 0; j < TN; j++) acc[i][j] = {0.f, 0.f, 0.f, 0.f};

  // rowsum accumulators: EPI 4 uses TN-indexed col-sums (rowsum of Bt rows)
  float4v acc_rs[TN];
#pragma unroll
  for (int i = 0; i < TN; i++) acc_rs[i] = {0.f, 0.f, 0.f, 0.f};
  short8 ones;
#pragma unroll
  for (int e = 0; e < 8; e++) ones[e] = (short)0x3F80;  // bf16 1.0

  for (int k0 = 0; k0 < K; k0 += 64) {
    __syncthreads();  // B1: drains stage(k0) [vmcnt(0)] + wave sync

    short8 af[2][TM], bfr[2][TN];
#pragma unroll
    for (int s = 0; s < 2; s++) {
#pragma unroll
      for (int i = 0; i < TM; i++) {
        int R = wm + i * 16 + lane16;
        af[s][i] = *(const short8*)&As[R * 64 + (((s * 4 + q) ^ (R & 7)) * 8)];
      }
#pragma unroll
      for (int j = 0; j < TN; j++) {
        int R = wn + j * 16 + lane16;
        bfr[s][j] = *(const short8*)&Bs[R * 64 + (((s * 4 + q) ^ (R & 7)) * 8)];
      }
    }
    __syncthreads();  // B2: all waves done reading LDS

    if (k0 + 64 < K) stage(k0 + 64);  // async; overlaps the MFMA pack below

#pragma unroll
    for (int s = 0; s < 2; s++) {
      if (EPI == 4) {  // rowsum of Bt rows (Es rows q): C[m][n] = sum_k B[n][k]
#pragma unroll
        for (int j = 0; j < TN; j++)
          acc_rs[j] = __builtin_amdgcn_mfma_f32_16x16x32_bf16(ones, bfr[s][j], acc_rs[j], 0, 0, 0);
      }
#pragma unroll
      for (int i = 0; i < TM; i++) {
#pragma unroll
        for (int j = 0; j < TN; j++)
          acc[i][j] = __builtin_amdgcn_mfma_f32_16x16x32_bf16(af[s][i], bfr[s][j], acc[i][j], 0, 0, 0);
      }
    }
  }

#pragma unroll
  for (int i = 0; i < TM; i++) {
    int mrow = m0 + wm + i * 16 + q * 4;
    if (EPI == 0) {
#pragma unroll
      for (int j = 0; j < TN; j++) {
        int ncol = n0 + wn + j * 16 + lane16;   // tile-uniform branch: bounds %16
        if (ncol < 1536) {
          short* dst = ncol < 768 ? Cs : C1;
          const float* bs = ncol < 768 ? bias0 : bias1;
          int c = ncol < 768 ? ncol : ncol - 768;   // NOT `& 767` (768 != pow2)
#pragma unroll
          for (int rr = 0; rr < 4; rr++)
            dst[(long)(mrow + rr) * 768 + c] = f2bf(acc[i][j][rr] + bs[c]);
        } else {
          int e = ncol - 1536;
          float bv = bias2[e];
          short4v o;
#pragma unroll
          for (int rr = 0; rr < 4; rr++) o[rr] = f2bf(acc[i][j][rr] + bv);
          *(short4v*)&C2[(long)e * VLD + mrow] = o;   // Vt[e][m], padded ld
        }
      }
    } else {  // EPI == 4: rows = e, cols = q; out[q][e] = val / rowsum_q
#pragma unroll
      for (int j = 0; j < TN; j++) {
        int ncol = n0 + wn + j * 16 + lane16;       // q token
        float inv = 1.0f / acc_rs[j][0];            // rowsum_q (rr-independent)
        float4v o;
#pragma unroll
        for (int rr = 0; rr < 4; rr++) o[rr] = acc[i][j][rr] * inv;
        *(float4v*)&Cf[(long)ncol * ldc + mrow] = o;  // 16-B aligned (mrow%4==0)
      }
    }
  }
}

// ---------------------------------------------------------------------------
// 256x256 8-phase kernel — Es only (grid 8x8x4 = 256 blocks = perfect CU fit).
// 512 thr = 8 waves (2Mx4N), wave tile 128x64, BK=64, LDS 128 KiB dbuf.
// Per K-tile: 4 phases {ds_read subtile | stage 1 half-tile | barrier |
// lgkmcnt(0) | setprio(1) 16 MFMA setprio(0) | barrier}; vmcnt(6) at phase 4.
// ---------------------------------------------------------------------------
template<int EPI>
__global__ __launch_bounds__(512, 2)
void gemm8p(const short* __restrict__ A, const short* __restrict__ Bt,
            void* __restrict__ C0v, short* __restrict__ C1, short* __restrict__ C2,
            const float* __restrict__ bias0, const float* __restrict__ bias1,
            const float* __restrict__ bias2,
            int K, int lda, int ldb, int ldc,
            long sA, long sB, long sC, float scale) {
  const int b = blockIdx.z;
  A += (long)b * sA;
  Bt += (long)b * sB;
  short* Cs = (short*)C0v + (long)b * sC;

  __shared__ short As[2][256 * 64];   // [buf][row][64 shorts = 128 B, swizzled]
  __shared__ short Bs[2][256 * 64];

  const int t = threadIdx.x;
  const int wave = t >> 6, lane = t & 63;
  const int lane16 = lane & 15, q = lane >> 4;
  const int xr = lane16 & 7;            // row&7 for all fragment reads
  const int m0 = blockIdx.y * 256, n0 = blockIdx.x * 256;
  const int wm = (wave >> 2) * 128, wn = (wave & 3) * 64;
  const int rsub = lane >> 3;           // row within an 8-row / 1 KB wave-instr
  const int g = (lane & 7) ^ rsub;      // swizzled source chunk
  const int nt = K >> 6;

  // A stage-unit u: rows {u*64..u*64+63} U {128+u*64..}, dead after phase 1/3
  auto stageA = [&](int u, int tt) {
    short* dst = &As[tt & 1][0];
    const short* src = A + tt * 64 + g * 8;
#pragma unroll
    for (int r = 0; r < 2; r++) {
      int row0 = u * 64 + r * 128 + wave * 8;
      glds16(src + (long)(m0 + row0 + rsub) * lda, dst + row0 * 64);
    }
  };
  // B stage-unit u: rows {64k+u*32 .. 64k+u*32+31}, dead after phase 1/2
  auto stageB = [&](int u, int tt) {
    short* dst = &Bs[tt & 1][0];
    const short* src = Bt + tt * 64 + g * 8;
#pragma unroll
    for (int r = 0; r < 2; r++) {
      int idx = r * 8 + wave;
      int row0 = (idx >> 2) * 64 + u * 32 + (idx & 3) * 8;
      glds16(src + (long)(n0 + row0 + rsub) * ldb, dst + row0 * 64);
    }
  };

  float4v acc[8][4];
#pragma unroll
  for (int i = 0; i < 8; i++)
#pragma unroll
    for (int j = 0; j < 4; j++) acc[i][j] = {0.f, 0.f, 0.f, 0.f};

  // prologue: tile0 fully, tile1 first 3 units (order = steady-state order)
  stageA(0, 0); stageA(1, 0); stageB(0, 0); stageB(1, 0);
  if (nt > 1) { stageA(0, 1); stageB(0, 1); stageA(1, 1); }
  if (nt > 1) asm volatile("s_waitcnt vmcnt(6)" ::: "memory");
  else        asm volatile("s_waitcnt vmcnt(0)" ::: "memory");
  __builtin_amdgcn_s_barrier();

#pragma unroll 2
  for (int tt = 0; tt < nt; ++tt) {
    const short* Ab = &As[tt & 1][0];
    const short* Bb = &Bs[tt & 1][0];
    short8 a[4][2], b0[2][2], b1[2][2];

    // ---- phase 1: quadrant (mh0, nh0); stage (tt+1).B-u1 into other buf
#pragma unroll
    for (int ii = 0; ii < 4; ii++) {
      int R = wm + ii * 16 + lane16;
#pragma unroll
      for (int s = 0; s < 2; s++)
        a[ii][s] = *(const short8*)&Ab[R * 64 + (((s * 4 + q) ^ xr) * 8)];
    }
#pragma unroll
    for (int jj = 0; jj < 2; jj++) {
      int R = wn + jj * 16 + lane16;
#pragma unroll
      for (int s = 0; s < 2; s++)
        b0[jj][s] = *(const short8*)&Bb[R * 64 + (((s * 4 + q) ^ xr) * 8)];
    }
    if (tt + 1 < nt) stageB(1, tt + 1);
    __builtin_amdgcn_s_barrier();
    asm volatile("s_waitcnt lgkmcnt(0)" ::: "memory");
    __builtin_amdgcn_sched_barrier(0);
    __builtin_amdgcn_s_setprio(1);
#pragma unroll
    for (int s = 0; s < 2; s++)
#pragma unroll
      for (int ii = 0; ii < 4; ii++)
#pragma unroll
        for (int jj = 0; jj < 2; jj++)
          acc[ii][jj] = __builtin_amdgcn_mfma_f32_16x16x32_bf16(a[ii][s], b0[jj][s], acc[ii][jj], 0, 0, 0);
    __builtin_amdgcn_s_setprio(0);
    __builtin_amdgcn_s_barrier();

    // ---- phase 2: quadrant (mh0, nh1); stage (tt+2).A-u0 (dead since ph1)
#pragma unroll
    for (int jj = 0; jj < 2; jj++) {
      int R = wn + 32 + jj * 16 + lane16;
#pragma unroll
      for (int s = 0; s < 2; s++)
        b1[jj][s] = *(const short8*)&Bb[R * 64 + (((s * 4 + q) ^ xr) * 8)];
    }
    if (tt + 2 < nt) stageA(0, tt + 2);
    __builtin_amdgcn_s_barrier();
    asm volatile("s_waitcnt lgkmcnt(0)" ::: "memory");
    __builtin_amdgcn_sched_barrier(0);
    __builtin_amdgcn_s_setprio(1);
#pragma unroll
    for (int s = 0; s < 2; s++)
#pragma unroll
      for (int ii = 0; ii < 4; ii++)
#pragma unroll
        for (int jj = 0; jj < 2; jj++)
          acc[ii][2 + jj] = __builtin_amdgcn_mfma_f32_16x16x32_bf16(a[ii][s], b1[jj][s], acc[ii][2 + jj], 0, 0, 0);
    __builtin_amdgcn_s_setprio(0);
    __builtin_amdgcn_s_barrier();

    // ---- phase 3: quadrant (mh1, nh1); A-u1 reads; stage (tt+2).B-u0
#pragma unroll
    for (int ii = 0; ii < 4; ii++) {
      int R = wm + 64 + ii * 16 + lane16;
#pragma unroll
      for (int s = 0; s < 2; s++)
        a[ii][s] = *(const short8*)&Ab[R * 64 + (((s * 4 + q) ^ xr) * 8)];
    }
    if (tt + 2 < nt) stageB(0, tt + 2);
    __builtin_amdgcn_s_barrier();
    asm volatile("s_waitcnt lgkmcnt(0)" ::: "memory");
    __builtin_amdgcn_sched_barrier(0);
    __builtin_amdgcn_s_setprio(1);
#pragma unroll
    for (int s = 0; s < 2; s++)
#pragma unroll
      for (int ii = 0; ii < 4; ii++)
#pragma unroll
        for (int jj = 0; jj < 2; jj++)
          acc[4 + ii][2 + jj] = __builtin_amdgcn_mfma_f32_16x16x32_bf16(a[ii][s], b1[jj][s], acc[4 + ii][2 + jj], 0, 0, 0);
    __builtin_amdgcn_s_setprio(0);
    __builtin_amdgcn_s_barrier();

    // ---- phase 4: quadrant (mh1, nh0); stage (tt+2).A-u1 (dead since ph3);
    //      counted vmcnt — guarantees tile tt+1 staged, 3 half-tiles in flight
    if (tt + 2 < nt) stageA(1, tt + 2);
    __builtin_amdgcn_s_barrier();
    __builtin_amdgcn_s_setprio(1);
#pragma unroll
    for (int s = 0; s < 2; s++)
#pragma unroll
      for (int ii = 0; ii < 4; ii++)
#pragma unroll
        for (int jj = 0; jj < 2; jj++)
          acc[4 + ii][jj] = __builtin_amdgcn_mfma_f32_16x16x32_bf16(a[ii][s], b0[jj][s], acc[4 + ii][jj], 0, 0, 0);
    __builtin_amdgcn_s_setprio(0);
    if (tt + 2 < nt) asm volatile("s_waitcnt vmcnt(6)" ::: "memory");
    else             asm volatile("s_waitcnt vmcnt(0)" ::: "memory");
    __builtin_amdgcn_s_barrier();
  }

  // epilogue (EPI == 2): bf16 out = exp(acc*scale)
#pragma unroll
  for (int i = 0; i < 8; i++) {
    int mrow = m0 + wm + i * 16 + q * 4;
#pragma unroll
    for (int j = 0; j < 4; j++) {
      int ncol = n0 + wn + j * 16 + lane16;
#pragma unroll
      for (int rr = 0; rr < 4; rr++)
        Cs[(long)(mrow + rr) * ldc + ncol] = f2bf(__expf(acc[i][j][rr] * scale));
    }
  }
}

extern "C" void kernel_launch(void* const* d_in, const int* in_sizes, int n_in,
                              void* d_out, int out_size, void* d_ws, size_t ws_size,
                              hipStream_t stream) {
  const float* x  = (const float*)d_in[0];
  const float* Wq = (const float*)d_in[1];
  const float* bq = (const float*)d_in[2];
  const float* Wk = (const float*)d_in[3];
  const float* bk = (const float*)d_in[4];
  const float* Wv = (const float*)d_in[5];
  const float* bv = (const float*)d_in[6];
  float* out = (float*)d_out;

  short* Xb  = (short*)d_ws;                     // [8192][768]
  short* WqT = Xb + (long)MS * D_;               // [2304][768] = WqT||WkT||WvT
  short* WkT = WqT + (long)D_ * D_;
  short* WvT = WkT + (long)D_ * D_;
  short* Qb  = WvT + (long)D_ * D_;              // [8192][768]
  short* Kb  = Qb + (long)MS * D_;               // [8192][768]
  short* Vt  = Kb + (long)MS * D_;               // [768][VLD]  (padded)
  short* Es  = Vt + (long)D_ * VLD;              // [4][2048][ELD] exp(scores)

  cast_f32_bf16<<<(MS * D_) / 1024, 256, 0, stream>>>(x, Xb, MS * D_);
  transpose_cast_w<<<dim3(24, 24, 3), dim3(32, 8), 0, stream>>>(Wq, Wk, Wv, WqT, WkT, WvT);

  // Q||K||Vt = Xb @ [WqT;WkT;WvT]^T + biases  (128x128 2-phase, 18x64 blk)
  gemm_bt<0, 4, 4><<<dim3(2304 / 128, MS / 128, 1), 256, 0, stream>>>(
      Xb, WqT, Qb, Kb, Vt, bq, bk, bv,
      D_, D_, D_, D_, 0, 0, 0, 1.0f);
  // Es[b,q,k] = exp((Qb[b] @ Kb[b]^T)/sqrt(D)) -> bf16, ld ELD  (8x8x4 = 256 blk)
  gemm8p<2><<<dim3(S_ / 256, S_ / 256, B_), 512, 0, stream>>>(
      Qb, Kb, Es, nullptr, nullptr, nullptr, nullptr, nullptr,
      D_, D_, D_, ELD,
      (long)S_ * D_, (long)S_ * D_, (long)S_ * ELD, 1.0f / sqrtf((float)D_));
  // O^T-form PV: C'[e][q] = Vt[b] @ Es[b]^T; out[q][e] = C'/rowsum_q
  // A = Vt (lda=VLD, batch col-window sA=2048), Bt = Es (ldb=ELD)
  gemm_bt<4, 4, 4><<<dim3(S_ / 128, D_ / 128, B_), 256, 0, stream>>>(
      Vt, Es, out, nullptr, nullptr, nullptr, nullptr, nullptr,
      S_, VLD, ELD, D_,
      (long)S_, (long)S_ * ELD, (long)S_ * D_, 1.0f);
}

// Round 5
// 195.884 us; speedup vs baseline: 1.1063x; 1.0414x over previous
//
#include <hip/hip_runtime.h>
#include <hip/hip_bf16.h>

// Self-attention: B=4, S=2048, D=768, fp32 in/out, bf16 MFMA internally.
// R11: base = R8 exact config (best measured: QKV 128x128 2-phase, Es 256x256
// 8-phase 256-blk perfect fit, PV flipped 2-phase full-K; R10's row pads
// reverted — padding measured null: PV scaled exactly with session clock).
// Single change: XCD-chunked blockIdx swizzle (T1) in both GEMM kernels.
// Counters show 4x A/B-panel overfetch (QKV FETCH 64MB vs 16 compulsory)
// from round-robin block->XCD assignment; chunked remap makes each XCD's
// private L2 hold one panel working set. All per-z grids %8==0 (1152/64/96)
// so nid=(oid&7)*(nxy/8)+(oid>>3) is bijective and z-phase-consistent.
// ws: Xb | WqT WkT WvT | Qb Kb Vt | Es

typedef __attribute__((ext_vector_type(8))) short short8;
typedef __attribute__((ext_vector_type(4))) short short4v;
typedef __attribute__((ext_vector_type(4))) float float4v;

static constexpr int B_ = 4, S_ = 2048, D_ = 768;
static constexpr int MS = B_ * S_;  // 8192

__device__ inline short f2bf(float f) {
  __hip_bfloat16 h = __float2bfloat16(f);
  union { __hip_bfloat16 h; short s; } u; u.h = h; return u.s;
}

typedef const __attribute__((address_space(1))) unsigned int g_u32;
typedef __attribute__((address_space(3))) unsigned int l_u32;

__device__ __forceinline__ void glds16(const short* g, short* l) {
  __builtin_amdgcn_global_load_lds((g_u32*)g, (l_u32*)l, 16, 0, 0);
}

// XCD-chunked bijective remap (valid when (gridDim.x*gridDim.y) % 8 == 0):
// original consecutive ids round-robin XCDs; remap so ids on one XCD form a
// contiguous tile chunk (panel reuse lands in that XCD's private L2).
__device__ __forceinline__ void xcd_swizzle(int& bx, int& by) {
  const int gx = gridDim.x, nxy = gx * gridDim.y;
  const int oid = blockIdx.y * gx + blockIdx.x;
  const int nid = (oid & 7) * (nxy >> 3) + (oid >> 3);
  bx = nid % gx;
  by = nid / gx;
}

__global__ __launch_bounds__(256)
void cast_f32_bf16(const float* __restrict__ x, short* __restrict__ y, int n) {
  int i = (blockIdx.x * 256 + threadIdx.x) * 4;
  if (i + 3 < n) {
    float4v v = *(const float4v*)(x + i);
    short4v o;
    o.x = f2bf(v.x); o.y = f2bf(v.y); o.z = f2bf(v.z); o.w = f2bf(v.w);
    *(short4v*)(y + i) = o;
  }
}

// T[e][d] = (bf16) W[d][e], for three 768x768 matrices
__global__ void transpose_cast_w(const float* __restrict__ W0, const float* __restrict__ W1,
                                 const float* __restrict__ W2,
                                 short* __restrict__ T0, short* __restrict__ T1,
                                 short* __restrict__ T2) {
  const float* W = blockIdx.z == 0 ? W0 : (blockIdx.z == 1 ? W1 : W2);
  short* T = blockIdx.z == 0 ? T0 : (blockIdx.z == 1 ? T1 : T2);
  __shared__ float tile[32][33];
  int bx = blockIdx.x * 32, by = blockIdx.y * 32;
  int tx = threadIdx.x, ty = threadIdx.y;
  for (int r = ty; r < 32; r += 8)
    tile[r][tx] = W[(by + r) * D_ + bx + tx];
  __syncthreads();
  for (int r = ty; r < 32; r += 8)
    T[(bx + r) * D_ + by + tx] = f2bf(tile[tx][r]);
}

// ---------------------------------------------------------------------------
// 128x128 2-phase kernel. EPI 0: QKV tri-output. EPI 4: flipped PV —
// C'[e][q] = sum_k Vt[e][k]*Es[q][k]; out[q][e] = C'/rowsum_q, float4 stores.
// ---------------------------------------------------------------------------
template<int EPI, int TM, int TN>
__global__ __launch_bounds__(256)
void gemm_bt(const short* __restrict__ A, const short* __restrict__ Bt,
             void* __restrict__ C0v, short* __restrict__ C1, short* __restrict__ C2,
             const float* __restrict__ bias0, const float* __restrict__ bias1,
             const float* __restrict__ bias2,
             int K, int lda, int ldb, int ldc,
             long sA, long sB, long sC, float scale) {
  constexpr int BMv = TM * 32, BNv = TN * 32;
  const int b = blockIdx.z;
  A += (long)b * sA;
  Bt += (long)b * sB;
  float* Cf = (float*)C0v + (long)b * sC;
  short* Cs = (short*)C0v + (long)b * sC;

  __shared__ short As[BMv * 64];
  __shared__ short Bs[BNv * 64];

  const int t = threadIdx.x;
  const int wave = t >> 6, lane = t & 63;
  const int lane16 = lane & 15, q = lane >> 4;
  int bxs, bys;
  xcd_swizzle(bxs, bys);
  const int m0 = bys * BMv, n0 = bxs * BNv;
  const int wm = (wave >> 1) * (TM * 16), wn = (wave & 1) * (TN * 16);
  const int rsub = lane >> 3;
  const int g = (lane & 7) ^ rsub;

  auto stage = [&](int kk) {
#pragma unroll
    for (int i = wave; i < BMv / 8; i += 4)
      glds16(A + (long)(m0 + i * 8 + rsub) * lda + kk + g * 8, &As[i * 512]);
#pragma unroll
    for (int i = wave; i < BNv / 8; i += 4)
      glds16(Bt + (long)(n0 + i * 8 + rsub) * ldb + kk + g * 8, &Bs[i * 512]);
  };

  stage(0);

  float4v acc[TM][TN];
#pragma unroll
  for (int i = 0; i < TM; i++)
#pragma unroll
    for (int j = 0; j < TN; j++) acc[i][j] = {0.f, 0.f, 0.f, 0.f};

  // rowsum accumulators: EPI 4 uses TN-indexed col-sums (rowsum of Bt rows)
  float4v acc_rs[TN];
#pragma unroll
  for (int i = 0; i < TN; i++) acc_rs[i] = {0.f, 0.f, 0.f, 0.f};
  short8 ones;
#pragma unroll
  for (int e = 0; e < 8; e++) ones[e] = (short)0x3F80;  // bf16 1.0

  for (int k0 = 0; k0 < K; k0 += 64) {
    __syncthreads();  // B1: drains stage(k0) [vmcnt(0)] + wave sync

    short8 af[2][TM], bfr[2][TN];
#pragma unroll
    for (int s = 0; s < 2; s++) {
#pragma unroll
      for (int i = 0; i < TM; i++) {
        int R = wm + i * 16 + lane16;
        af[s][i] = *(const short8*)&As[R * 64 + (((s * 4 + q) ^ (R & 7)) * 8)];
      }
#pragma unroll
      for (int j = 0; j < TN; j++) {
        int R = wn + j * 16 + lane16;
        bfr[s][j] = *(const short8*)&Bs[R * 64 + (((s * 4 + q) ^ (R & 7)) * 8)];
      }
    }
    __syncthreads();  // B2: all waves done reading LDS

    if (k0 + 64 < K) stage(k0 + 64);  // async; overlaps the MFMA pack below

#pragma unroll
    for (int s = 0; s < 2; s++) {
      if (EPI == 4) {  // rowsum of Bt rows (Es rows q): C[m][n] = sum_k B[n][k]
#pragma unroll
        for (int j = 0; j < TN; j++)
          acc_rs[j] = __builtin_amdgcn_mfma_f32_16x16x32_bf16(ones, bfr[s][j], acc_rs[j], 0, 0, 0);
      }
#pragma unroll
      for (int i = 0; i < TM; i++) {
#pragma unroll
        for (int j = 0; j < TN; j++)
          acc[i][j] = __builtin_amdgcn_mfma_f32_16x16x32_bf16(af[s][i], bfr[s][j], acc[i][j], 0, 0, 0);
      }
    }
  }

#pragma unroll
  for (int i = 0; i < TM; i++) {
    int mrow = m0 + wm + i * 16 + q * 4;
    if (EPI == 0) {
#pragma unroll
      for (int j = 0; j < TN; j++) {
        int ncol = n0 + wn + j * 16 + lane16;   // tile-uniform branch: bounds %16
        if (ncol < 1536) {
          short* dst = ncol < 768 ? Cs : C1;
          const float* bs = ncol < 768 ? bias0 : bias1;
          int c = ncol < 768 ? ncol : ncol - 768;   // NOT `& 767` (768 != pow2)
#pragma unroll
          for (int rr = 0; rr < 4; rr++)
            dst[(long)(mrow + rr) * 768 + c] = f2bf(acc[i][j][rr] + bs[c]);
        } else {
          int e = ncol - 1536;
          float bv = bias2[e];
          short4v o;
#pragma unroll
          for (int rr = 0; rr < 4; rr++) o[rr] = f2bf(acc[i][j][rr] + bv);
          *(short4v*)&C2[(long)e * MS + mrow] = o;   // Vt[e][m], 8-B store
        }
      }
    } else {  // EPI == 4: rows = e, cols = q; out[q][e] = val / rowsum_q
#pragma unroll
      for (int j = 0; j < TN; j++) {
        int ncol = n0 + wn + j * 16 + lane16;       // q token
        float inv = 1.0f / acc_rs[j][0];            // rowsum_q (rr-independent)
        float4v o;
#pragma unroll
        for (int rr = 0; rr < 4; rr++) o[rr] = acc[i][j][rr] * inv;
        *(float4v*)&Cf[(long)ncol * ldc + mrow] = o;  // 16-B aligned (mrow%4==0)
      }
    }
  }
}

// ---------------------------------------------------------------------------
// 256x256 8-phase kernel — Es only (grid 8x8x4 = 256 blocks = perfect CU fit).
// 512 thr = 8 waves (2Mx4N), wave tile 128x64, BK=64, LDS 128 KiB dbuf.
// Per K-tile: 4 phases {ds_read subtile | stage 1 half-tile | barrier |
// lgkmcnt(0) | setprio(1) 16 MFMA setprio(0) | barrier}; vmcnt(6) at phase 4.
// ---------------------------------------------------------------------------
template<int EPI>
__global__ __launch_bounds__(512, 2)
void gemm8p(const short* __restrict__ A, const short* __restrict__ Bt,
            void* __restrict__ C0v, short* __restrict__ C1, short* __restrict__ C2,
            const float* __restrict__ bias0, const float* __restrict__ bias1,
            const float* __restrict__ bias2,
            int K, int lda, int ldb, int ldc,
            long sA, long sB, long sC, float scale) {
  const int b = blockIdx.z;
  A += (long)b * sA;
  Bt += (long)b * sB;
  short* Cs = (short*)C0v + (long)b * sC;

  __shared__ short As[2][256 * 64];   // [buf][row][64 shorts = 128 B, swizzled]
  __shared__ short Bs[2][256 * 64];

  const int t = threadIdx.x;
  const int wave = t >> 6, lane = t & 63;
  const int lane16 = lane & 15, q = lane >> 4;
  const int xr = lane16 & 7;            // row&7 for all fragment reads
  int bxs, bys;
  xcd_swizzle(bxs, bys);
  const int m0 = bys * 256, n0 = bxs * 256;
  const int wm = (wave >> 2) * 128, wn = (wave & 3) * 64;
  const int rsub = lane >> 3;           // row within an 8-row / 1 KB wave-instr
  const int g = (lane & 7) ^ rsub;      // swizzled source chunk
  const int nt = K >> 6;

  // A stage-unit u: rows {u*64..u*64+63} U {128+u*64..}, dead after phase 1/3
  auto stageA = [&](int u, int tt) {
    short* dst = &As[tt & 1][0];
    const short* src = A + tt * 64 + g * 8;
#pragma unroll
    for (int r = 0; r < 2; r++) {
      int row0 = u * 64 + r * 128 + wave * 8;
      glds16(src + (long)(m0 + row0 + rsub) * lda, dst + row0 * 64);
    }
  };
  // B stage-unit u: rows {64k+u*32 .. 64k+u*32+31}, dead after phase 1/2
  auto stageB = [&](int u, int tt) {
    short* dst = &Bs[tt & 1][0];
    const short* src = Bt + tt * 64 + g * 8;
#pragma unroll
    for (int r = 0; r < 2; r++) {
      int idx = r * 8 + wave;
      int row0 = (idx >> 2) * 64 + u * 32 + (idx & 3) * 8;
      glds16(src + (long)(n0 + row0 + rsub) * ldb, dst + row0 * 64);
    }
  };

  float4v acc[8][4];
#pragma unroll
  for (int i = 0; i < 8; i++)
#pragma unroll
    for (int j = 0; j < 4; j++) acc[i][j] = {0.f, 0.f, 0.f, 0.f};

  // prologue: tile0 fully, tile1 first 3 units (order = steady-state order)
  stageA(0, 0); stageA(1, 0); stageB(0, 0); stageB(1, 0);
  if (nt > 1) { stageA(0, 1); stageB(0, 1); stageA(1, 1); }
  if (nt > 1) asm volatile("s_waitcnt vmcnt(6)" ::: "memory");
  else        asm volatile("s_waitcnt vmcnt(0)" ::: "memory");
  __builtin_amdgcn_s_barrier();

#pragma unroll 2
  for (int tt = 0; tt < nt; ++tt) {
    const short* Ab = &As[tt & 1][0];
    const short* Bb = &Bs[tt & 1][0];
    short8 a[4][2], b0[2][2], b1[2][2];

    // ---- phase 1: quadrant (mh0, nh0); stage (tt+1).B-u1 into other buf
#pragma unroll
    for (int ii = 0; ii < 4; ii++) {
      int R = wm + ii * 16 + lane16;
#pragma unroll
      for (int s = 0; s < 2; s++)
        a[ii][s] = *(const short8*)&Ab[R * 64 + (((s * 4 + q) ^ xr) * 8)];
    }
#pragma unroll
    for (int jj = 0; jj < 2; jj++) {
      int R = wn + jj * 16 + lane16;
#pragma unroll
      for (int s = 0; s < 2; s++)
        b0[jj][s] = *(const short8*)&Bb[R * 64 + (((s * 4 + q) ^ xr) * 8)];
    }
    if (tt + 1 < nt) stageB(1, tt + 1);
    __builtin_amdgcn_s_barrier();
    asm volatile("s_waitcnt lgkmcnt(0)" ::: "memory");
    __builtin_amdgcn_sched_barrier(0);
    __builtin_amdgcn_s_setprio(1);
#pragma unroll
    for (int s = 0; s < 2; s++)
#pragma unroll
      for (int ii = 0; ii < 4; ii++)
#pragma unroll
        for (int jj = 0; jj < 2; jj++)
          acc[ii][jj] = __builtin_amdgcn_mfma_f32_16x16x32_bf16(a[ii][s], b0[jj][s], acc[ii][jj], 0, 0, 0);
    __builtin_amdgcn_s_setprio(0);
    __builtin_amdgcn_s_barrier();

    // ---- phase 2: quadrant (mh0, nh1); stage (tt+2).A-u0 (dead since ph1)
#pragma unroll
    for (int jj = 0; jj < 2; jj++) {
      int R = wn + 32 + jj * 16 + lane16;
#pragma unroll
      for (int s = 0; s < 2; s++)
        b1[jj][s] = *(const short8*)&Bb[R * 64 + (((s * 4 + q) ^ xr) * 8)];
    }
    if (tt + 2 < nt) stageA(0, tt + 2);
    __builtin_amdgcn_s_barrier();
    asm volatile("s_waitcnt lgkmcnt(0)" ::: "memory");
    __builtin_amdgcn_sched_barrier(0);
    __builtin_amdgcn_s_setprio(1);
#pragma unroll
    for (int s = 0; s < 2; s++)
#pragma unroll
      for (int ii = 0; ii < 4; ii++)
#pragma unroll
        for (int jj = 0; jj < 2; jj++)
          acc[ii][2 + jj] = __builtin_amdgcn_mfma_f32_16x16x32_bf16(a[ii][s], b1[jj][s], acc[ii][2 + jj], 0, 0, 0);
    __builtin_amdgcn_s_setprio(0);
    __builtin_amdgcn_s_barrier();

    // ---- phase 3: quadrant (mh1, nh1); A-u1 reads; stage (tt+2).B-u0
#pragma unroll
    for (int ii = 0; ii < 4; ii++) {
      int R = wm + 64 + ii * 16 + lane16;
#pragma unroll
      for (int s = 0; s < 2; s++)
        a[ii][s] = *(const short8*)&Ab[R * 64 + (((s * 4 + q) ^ xr) * 8)];
    }
    if (tt + 2 < nt) stageB(0, tt + 2);
    __builtin_amdgcn_s_barrier();
    asm volatile("s_waitcnt lgkmcnt(0)" ::: "memory");
    __builtin_amdgcn_sched_barrier(0);
    __builtin_amdgcn_s_setprio(1);
#pragma unroll
    for (int s = 0; s < 2; s++)
#pragma unroll
      for (int ii = 0; ii < 4; ii++)
#pragma unroll
        for (int jj = 0; jj < 2; jj++)
          acc[4 + ii][2 + jj] = __builtin_amdgcn_mfma_f32_16x16x32_bf16(a[ii][s], b1[jj][s], acc[4 + ii][2 + jj], 0, 0, 0);
    __builtin_amdgcn_s_setprio(0);
    __builtin_amdgcn_s_barrier();

    // ---- phase 4: quadrant (mh1, nh0); stage (tt+2).A-u1 (dead since ph3);
    //      counted vmcnt — guarantees tile tt+1 staged, 3 half-tiles in flight
    if (tt + 2 < nt) stageA(1, tt + 2);
    __builtin_amdgcn_s_barrier();
    __builtin_amdgcn_s_setprio(1);
#pragma unroll
    for (int s = 0; s < 2; s++)
#pragma unroll
      for (int ii = 0; ii < 4; ii++)
#pragma unroll
        for (int jj = 0; jj < 2; jj++)
          acc[4 + ii][jj] = __builtin_amdgcn_mfma_f32_16x16x32_bf16(a[ii][s], b0[jj][s], acc[4 + ii][jj], 0, 0, 0);
    __builtin_amdgcn_s_setprio(0);
    if (tt + 2 < nt) asm volatile("s_waitcnt vmcnt(6)" ::: "memory");
    else             asm volatile("s_waitcnt vmcnt(0)" ::: "memory");
    __builtin_amdgcn_s_barrier();
  }

  // epilogue (EPI == 2): bf16 out = exp(acc*scale)
#pragma unroll
  for (int i = 0; i < 8; i++) {
    int mrow = m0 + wm + i * 16 + q * 4;
#pragma unroll
    for (int j = 0; j < 4; j++) {
      int ncol = n0 + wn + j * 16 + lane16;
#pragma unroll
      for (int rr = 0; rr < 4; rr++)
        Cs[(long)(mrow + rr) * ldc + ncol] = f2bf(__expf(acc[i][j][rr] * scale));
    }
  }
}

extern "C" void kernel_launch(void* const* d_in, const int* in_sizes, int n_in,
                              void* d_out, int out_size, void* d_ws, size_t ws_size,
                              hipStream_t stream) {
  const float* x  = (const float*)d_in[0];
  const float* Wq = (const float*)d_in[1];
  const float* bq = (const float*)d_in[2];
  const float* Wk = (const float*)d_in[3];
  const float* bk = (const float*)d_in[4];
  const float* Wv = (const float*)d_in[5];
  const float* bv = (const float*)d_in[6];
  float* out = (float*)d_out;

  short* Xb  = (short*)d_ws;                     // [8192][768]
  short* WqT = Xb + (long)MS * D_;               // [2304][768] = WqT||WkT||WvT
  short* WkT = WqT + (long)D_ * D_;
  short* WvT = WkT + (long)D_ * D_;
  short* Qb  = WvT + (long)D_ * D_;              // [8192][768]
  short* Kb  = Qb + (long)MS * D_;               // [8192][768]
  short* Vt  = Kb + (long)MS * D_;               // [768][8192]
  short* Es  = Vt + (long)MS * D_;               // [4][2048][2048] exp(scores)

  cast_f32_bf16<<<(MS * D_) / 1024, 256, 0, stream>>>(x, Xb, MS * D_);
  transpose_cast_w<<<dim3(24, 24, 3), dim3(32, 8), 0, stream>>>(Wq, Wk, Wv, WqT, WkT, WvT);

  // Q||K||Vt = Xb @ [WqT;WkT;WvT]^T + biases  (128x128 2-phase, 18x64 blk)
  gemm_bt<0, 4, 4><<<dim3(2304 / 128, MS / 128, 1), 256, 0, stream>>>(
      Xb, WqT, Qb, Kb, Vt, bq, bk, bv,
      D_, D_, D_, D_, 0, 0, 0, 1.0f);
  // Es[b,q,k] = exp((Qb[b] @ Kb[b]^T)/sqrt(D)) -> bf16  (8x8x4 = 256 blk, 8-phase)
  gemm8p<2><<<dim3(S_ / 256, S_ / 256, B_), 512, 0, stream>>>(
      Qb, Kb, Es, nullptr, nullptr, nullptr, nullptr, nullptr,
      D_, D_, D_, S_,
      (long)S_ * D_, (long)S_ * D_, (long)S_ * S_, 1.0f / sqrtf((float)D_));
  // O^T-form PV: C'[e][q] = Vt[b] @ Es[b]^T; out[q][e] = C'/rowsum_q
  // A = Vt (lda=8192, batch col-window sA=2048), Bt = Es (ldb=2048, sB=S*S)
  gemm_bt<4, 4, 4><<<dim3(S_ / 128, D_ / 128, B_), 256, 0, stream>>>(
      Vt, Es, out, nullptr, nullptr, nullptr, nullptr, nullptr,
      S_, MS, S_, D_,
      (long)S_, (long)S_ * S_, (long)S_ * D_, 1.0f);
}